// Round 17
// baseline (69.868 us; speedup 1.0000x reference)
//
#include <hip/hip_runtime.h>
#include <hip/hip_bf16.h>

#define N_NODES 4096
#define IN_F 256
#define OUT_F 64
#define HEADS 8
#define ALPHA 0.2f

typedef _Float16 f16x8 __attribute__((ext_vector_type(8)));
typedef float f32x4 __attribute__((ext_vector_type(4)));
union U4 { uint4 u; f16x8 h; unsigned w[4]; };

// ---- workspace layout (bytes) ----
#define WFRAG_OFF 0                                 // 256 KB f16 W B-frags
#define BFRAG_OFF (WFRAG_OFF + 8*8*4*64*8*2)        // 4 MB  f16 H B-frags
#define F1_OFF    (BFRAG_OFF + 8*128*4*64*8*2)      // 128 KB f32 f1
#define GP_OFF    (F1_OFF + 8*4096*4)               // 64 KB f16 exp(f2)
#define GN_OFF    (GP_OFF + 8*4096*2)               // 64 KB f16 exp(a*f2)
#define ADJ_OFF   (GN_OFF + 8*4096*2)               // 2 MB adjacency bitmask

static __device__ __forceinline__ unsigned pkmul(unsigned a, unsigned b) {
  unsigned r; asm("v_pk_mul_f16 %0, %1, %2" : "=v"(r) : "v"(a), "v"(b)); return r;
}
static __device__ __forceinline__ unsigned pkmax(unsigned a, unsigned b) {
  unsigned r; asm("v_pk_max_f16 %0, %1, %2" : "=v"(r) : "v"(a), "v"(b)); return r;
}
static __device__ __forceinline__ unsigned pkadd(unsigned a, unsigned b) {
  unsigned r; asm("v_pk_add_f16 %0, %1, %2" : "=v"(r) : "v"(a), "v"(b)); return r;
}
static __device__ __forceinline__ unsigned short f2h_bits(float f) {
  return __builtin_bit_cast(unsigned short, (_Float16)f);
}
static __device__ __forceinline__ float h2f(unsigned short x) {
  return (float)__builtin_bit_cast(_Float16, x);
}

// k_pre: [0,8) W -> B-frag layout; [8,16) zero out
__global__ __launch_bounds__(256) void k_pre(const float* __restrict__ W,
                                             _Float16* __restrict__ wfrag,
                                             float* __restrict__ out) {
  int b = blockIdx.x, t = threadIdx.x;
  if (b < 8) {
    int h = b;
    for (int pos = t; pos < 2048; pos += 256) {
      int kt = pos >> 8, ct = (pos >> 6) & 3, l = pos & 63;
      int lr = l & 15, lg = l >> 4;
#pragma unroll
      for (int e = 0; e < 8; ++e)
        wfrag[(size_t)(((h*8 + kt)*4 + ct)*64 + l) * 8 + e]
          = (_Float16)W[(size_t)(h*256 + kt*32 + lg*8 + e) * 64 + ct*16 + lr];
    }
  } else {
    float4* oz = ((float4*)out) + (size_t)(b - 8) * 8192;
    float4 zz = make_float4(0.f, 0.f, 0.f, 0.f);
    for (int q = t; q < 8192; q += 256) oz[q] = zz;
  }
}

// k_main: ballot and GEMM blocks INTERLEAVED in dispatch order (b%5==4 -> GEMM)
__global__ __launch_bounds__(256) void k_main(
    const float* __restrict__ X, const int* __restrict__ adj,
    const _Float16* __restrict__ wfrag, const float* __restrict__ a,
    unsigned long long* __restrict__ bits, _Float16* __restrict__ bfrag,
    float* __restrict__ f1, _Float16* __restrict__ Gp, _Float16* __restrict__ Gn) {
  int b = blockIdx.x, t = threadIdx.x;
  if ((b % 5) != 4) {
    int b2 = (b / 5) * 4 + (b % 5);                // ballot index 0..2047
    int lane = t & 63;
    int waveid = b2 * 4 + (t >> 6);
#pragma unroll
    for (int it2 = 0; it2 < 8; ++it2) {
      int w0 = waveid + (it2*4 + 0) * 8192;
      int w1 = waveid + (it2*4 + 1) * 8192;
      int w2 = waveid + (it2*4 + 2) * 8192;
      int w3 = waveid + (it2*4 + 3) * 8192;
      int v0 = __builtin_nontemporal_load(adj + (size_t)w0 * 64 + lane);
      int v1 = __builtin_nontemporal_load(adj + (size_t)w1 * 64 + lane);
      int v2 = __builtin_nontemporal_load(adj + (size_t)w2 * 64 + lane);
      int v3 = __builtin_nontemporal_load(adj + (size_t)w3 * 64 + lane);
      unsigned long long m0 = __ballot(v0 != 0);
      unsigned long long m1 = __ballot(v1 != 0);
      unsigned long long m2 = __ballot(v2 != 0);
      unsigned long long m3 = __ballot(v3 != 0);
      if (lane == 0) { bits[w0] = m0; bits[w1] = m1; bits[w2] = m2; bits[w3] = m3; }
    }
    return;
  }
  int b2 = b / 5;                                  // GEMM index 0..511
  int h = b2 & 7, rb = b2 >> 3;
  int w = t >> 6, l = t & 63;
  int i0 = rb * 64 + w * 16;                       // 16 rows per wave
  int r = l & 15, g = l >> 4;
  const U4* wv = (const U4*)wfrag;
  f32x4 z = {0.f, 0.f, 0.f, 0.f};
  f32x4 acc[4] = {z, z, z, z};
#pragma unroll
  for (int kt = 0; kt < 8; ++kt) {
    const float4* xr = (const float4*)(X + (size_t)(i0 + r) * 256 + (kt*4 + g) * 8);
    float4 x0 = xr[0], x1 = xr[1];
    U4 af;
    af.h[0] = (_Float16)x0.x; af.h[1] = (_Float16)x0.y;
    af.h[2] = (_Float16)x0.z; af.h[3] = (_Float16)x0.w;
    af.h[4] = (_Float16)x1.x; af.h[5] = (_Float16)x1.y;
    af.h[6] = (_Float16)x1.z; af.h[7] = (_Float16)x1.w;
#pragma unroll
    for (int ct = 0; ct < 4; ++ct) {
      U4 bv = wv[((h*8 + kt)*4 + ct)*64 + l];
      acc[ct] = __builtin_amdgcn_mfma_f32_16x16x32_f16(af.h, bv.h, acc[ct], 0, 0, 0);
    }
  }
  int jb = i0 + g*4;
#pragma unroll
  for (int ct = 0; ct < 4; ++ct) {
    size_t base = ((((size_t)h*128 + (jb>>5))*4 + ct)*64 + ((jb>>3)&3)*16 + r) * 8
                  + (jb & 7);
    union { short4 s; _Float16 hh[4]; } sv;
#pragma unroll
    for (int ri = 0; ri < 4; ++ri) sv.hh[ri] = (_Float16)acc[ct][ri];
    *(short4*)(bfrag + base) = sv.s;
  }
  float a1v[4], a2v[4];
#pragma unroll
  for (int ct = 0; ct < 4; ++ct) {
    a1v[ct] = a[h*128 + ct*16 + r];
    a2v[ct] = a[h*128 + 64 + ct*16 + r];
  }
#pragma unroll
  for (int ri = 0; ri < 4; ++ri) {
    float s1 = acc[0][ri]*a1v[0] + acc[1][ri]*a1v[1]
             + acc[2][ri]*a1v[2] + acc[3][ri]*a1v[3];
    float s2 = acc[0][ri]*a2v[0] + acc[1][ri]*a2v[1]
             + acc[2][ri]*a2v[2] + acc[3][ri]*a2v[3];
#pragma unroll
    for (int off = 1; off < 16; off <<= 1) {
      s1 += __shfl_xor(s1, off);
      s2 += __shfl_xor(s2, off);
    }
    if (r == 0) {
      int row = i0 + g*4 + ri;
      f1[h*4096 + row] = s1;
      Gp[h*4096 + row] = (_Float16)__expf(s2);
      Gn[h*4096 + row] = (_Float16)__expf(ALPHA * s2);
    }
  }
}

// v6-exact body: MLUT mask, den via pkadd tree on the VALU pipe (no den-MFMA)
#define ATTN_BODY(PF, JT, DOPF) {                                              \
  U4 gp, gn;                                                                   \
  gp.u = Gs0[(JT)*4 + g].u;                                                    \
  gn.u = Gs1[(JT)*4 + g].u;                                                    \
  U4 b0, b1, b2, b3;                                                           \
  b0.u = PF[0]; b1.u = PF[1]; b2.u = PF[2]; b3.u = PF[3];                      \
  _Pragma("unroll")                                                            \
  for (int rg = 0; rg < 2; ++rg) {                                             \
    unsigned wm = Lb[rh32 + rg*16 + r][JT];                                    \
    U4 av;                                                                     \
    _Pragma("unroll")                                                          \
    for (int p = 0; p < 4; ++p) {                                              \
      unsigned pm = pkmax(pkmul(Epp[rg], gp.w[p]), pkmul(Enn[rg], gn.w[p]));   \
      av.w[p] = pm & MLUT[(wm >> (g8 + 2*p)) & 3u];                            \
    }                                                                          \
    acc[rg][0] = __builtin_amdgcn_mfma_f32_16x16x32_f16(av.h, b0.h, acc[rg][0], 0,0,0); \
    acc[rg][1] = __builtin_amdgcn_mfma_f32_16x16x32_f16(av.h, b1.h, acc[rg][1], 0,0,0); \
    acc[rg][2] = __builtin_amdgcn_mfma_f32_16x16x32_f16(av.h, b2.h, acc[rg][2], 0,0,0); \
    acc[rg][3] = __builtin_amdgcn_mfma_f32_16x16x32_f16(av.h, b3.h, acc[rg][3], 0,0,0); \
    unsigned sden = pkadd(pkadd(av.w[0], av.w[1]), pkadd(av.w[2], av.w[3]));   \
    den[rg] += h2f((unsigned short)(sden & 0xFFFFu))                           \
             + h2f((unsigned short)(sden >> 16));                              \
  }                                                                            \
  if (DOPF) {                                                                  \
    _Pragma("unroll")                                                          \
    for (int c = 0; c < 4; ++c) PF[c] = bfh[((JT) + 2)*256 + c*64];            \
  }                                                                            \
}

#define WRBUF(i) {                                                             \
  _Pragma("unroll")                                                            \
  for (int rg = 0; rg < 2; ++rg)                                               \
    _Pragma("unroll")                                                          \
    for (int ct = 0; ct < 4; ++ct) redp[(i)*576 + (rg*4+ct)*64 + l] = acc[rg][ct]; \
  f32x4 dv = {den[0], den[1], 0.f, 0.f};                                       \
  redp[(i)*576 + 512 + l] = dv;                                                \
}
#define ADBUF(i) {                                                             \
  _Pragma("unroll")                                                            \
  for (int rg = 0; rg < 2; ++rg)                                               \
    _Pragma("unroll")                                                          \
    for (int ct = 0; ct < 4; ++ct) acc[rg][ct] += redp[(i)*576 + (rg*4+ct)*64 + l]; \
  f32x4 dv = redp[(i)*576 + 512 + l];                                          \
  den[0] += dv[0]; den[1] += dv[1];                                            \
}

// k_attn v13 = r8's v6 exactly (pkadd den, MLUT mask, no den-MFMA, no setprio,
// no G-prefetch): block=(head, 64 rows) x 512 thr; 8 waves = 2 rh x 4 jq;
// 32 rows/wave -> acc 32 AGPR only; 2-deep private B prefetch.
__global__ __launch_bounds__(512, 4) void k_attn(
    const float* __restrict__ f1, const unsigned int* __restrict__ adjbits,
    const _Float16* __restrict__ Gp, const _Float16* __restrict__ Gn,
    const _Float16* __restrict__ bfrag, float* __restrict__ out) {
  __shared__ __align__(16) char smem[49408];
  __shared__ unsigned MLUT[4];
  unsigned (*Lb)[129] = (unsigned(*)[129])smem;    // 33024 B adjacency bits
  U4* Gs0 = (U4*)(smem + 33024);                   // 8 KB exp(f2)
  U4* Gs1 = (U4*)(smem + 41216);                   // 8 KB exp(a*f2)
  f32x4* redp = (f32x4*)smem;                      // overlay after main loop
  int b = blockIdx.x;
  int h = b & 7, rs = b >> 3;                      // head <-> XCD L2 locality
  int i0 = rs * 64;
  int t = threadIdx.x, wid = t >> 6, l = t & 63;
  int rh = wid >> 2, jq = wid & 3;
  int rh32 = rh * 32;
  int r = l & 15, g = l >> 4, g8 = g * 8;
  if (t < 4) MLUT[t] = ((t & 1) ? 0xFFFFu : 0u) | ((t & 2) ? 0xFFFF0000u : 0u);
  // B prefetch issued before staging (latency hidden under LDS fills)
  const uint4* bfh = (const uint4*)bfrag + (size_t)h * 32768 + l;
  int jt0 = jq * 32;
  uint4 pA[4], pB[4];
#pragma unroll
  for (int c = 0; c < 4; ++c) pA[c] = bfh[jt0 * 256 + c*64];
#pragma unroll
  for (int c = 0; c < 4; ++c) pB[c] = bfh[(jt0 + 1) * 256 + c*64];
  for (int q = t; q < 8192; q += 512)
    Lb[q >> 7][q & 127] = adjbits[(size_t)(i0 + (q >> 7)) * 128 + (q & 127)];
  Gs0[t].u = ((const uint4*)(Gp + (size_t)h * 4096))[t];
  Gs1[t].u = ((const uint4*)(Gn + (size_t)h * 4096))[t];
  unsigned Epp[2], Enn[2];
#pragma unroll
  for (int rg = 0; rg < 2; ++rg) {
    float f1r = f1[h * N_NODES + i0 + rh32 + rg*16 + r];
    unsigned short ep = f2h_bits(__expf(f1r));
    unsigned short en = f2h_bits(__expf(ALPHA * f1r));
    Epp[rg] = ep | ((unsigned)ep << 16);
    Enn[rg] = en | ((unsigned)en << 16);
  }
  __syncthreads();
  f32x4 z = {0.f,0.f,0.f,0.f};
  f32x4 acc[2][4] = {{z,z,z,z},{z,z,z,z}};
  float den[2] = {0.f, 0.f};
  for (int q2 = 0; q2 < 16; ++q2) {
    ATTN_BODY(pA, jt0 + q2*2,     (q2 < 15));
    ATTN_BODY(pB, jt0 + q2*2 + 1, (q2 < 15));
  }
  __syncthreads();                                 // Lb/Gs dead; redp overlays
  // cross-jq tree per rh: (jq1,jq3)->bufs, (jq0,jq2) add; jq2->buf, jq0 adds
  if (jq == 1 || jq == 3) WRBUF(rh*2 + (jq >> 1));
  __syncthreads();
  if (jq == 0) ADBUF(rh*2);
  if (jq == 2) ADBUF(rh*2 + 1);
  __syncthreads();
  if (jq == 2) WRBUF(rh);
  __syncthreads();
  if (jq == 0) {
    ADBUF(rh);
#pragma unroll
    for (int rg = 0; rg < 2; ++rg) {
      den[rg] += __shfl_xor(den[rg], 16);
      den[rg] += __shfl_xor(den[rg], 32);          // all lanes: den of row l&15
    }
#pragma unroll
    for (int rg = 0; rg < 2; ++rg)
#pragma unroll
      for (int ri = 0; ri < 4; ++ri) {
        float dr = __shfl(den[rg], g*4 + ri);      // lane g*4+ri holds that row
        float sc = 0.125f / dr;
        float* op = out + (size_t)(i0 + rh32 + rg*16 + g*4 + ri) * 64;
        atomicAdd(op + r,      acc[rg][0][ri] * sc);
        atomicAdd(op + 16 + r, acc[rg][1][ri] * sc);
        atomicAdd(op + 32 + r, acc[rg][2][ri] * sc);
        atomicAdd(op + 48 + r, acc[rg][3][ri] * sc);
      }
  }
}

extern "C" void kernel_launch(void* const* d_in, const int* in_sizes, int n_in,
                              void* d_out, int out_size, void* d_ws, size_t ws_size,
                              hipStream_t stream) {
  const float* X = (const float*)d_in[0];
  const int* adj = (const int*)d_in[1];
  const float* W = (const float*)d_in[2];
  const float* a = (const float*)d_in[3];
  float* out = (float*)d_out;
  char* ws = (char*)d_ws;

  _Float16* wfrag = (_Float16*)(ws + WFRAG_OFF);
  _Float16* bfrag = (_Float16*)(ws + BFRAG_OFF);
  float* f1 = (float*)(ws + F1_OFF);
  _Float16* Gp = (_Float16*)(ws + GP_OFF);
  _Float16* Gn = (_Float16*)(ws + GN_OFF);
  unsigned long long* bits64 = (unsigned long long*)(ws + ADJ_OFF);
  const unsigned int* bits32 = (const unsigned int*)(ws + ADJ_OFF);

  k_pre<<<dim3(16), dim3(256), 0, stream>>>(W, wfrag, out);
  k_main<<<dim3(2560), dim3(256), 0, stream>>>(X, adj, wfrag, a, bits64, bfrag,
                                               f1, Gp, Gn);
  k_attn<<<dim3(512), dim3(512), 0, stream>>>(f1, bits32, Gp, Gn, bfrag, out);
}

// Round 18
// 67.940 us; speedup vs baseline: 1.0284x; 1.0284x over previous
//
#include <hip/hip_runtime.h>
#include <hip/hip_bf16.h>

#define N_NODES 4096
#define IN_F 256
#define OUT_F 64
#define HEADS 8
#define ALPHA 0.2f

typedef _Float16 f16x8 __attribute__((ext_vector_type(8)));
typedef float f32x4 __attribute__((ext_vector_type(4)));
union U4 { uint4 u; f16x8 h; unsigned w[4]; };

// ---- workspace layout (bytes) ----
#define WFRAG_OFF 0                                 // 256 KB f16 W B-frags
#define BFRAG_OFF (WFRAG_OFF + 8*8*4*64*8*2)        // 4 MB  f16 H B-frags
#define F1_OFF    (BFRAG_OFF + 8*128*4*64*8*2)      // 128 KB f32 f1
#define GP_OFF    (F1_OFF + 8*4096*4)               // 64 KB f16 exp(f2)
#define GN_OFF    (GP_OFF + 8*4096*2)               // 64 KB f16 exp(a*f2)
#define ADJ_OFF   (GN_OFF + 8*4096*2)               // 2 MB adjacency bitmask

static __device__ __forceinline__ unsigned pkmul(unsigned a, unsigned b) {
  unsigned r; asm("v_pk_mul_f16 %0, %1, %2" : "=v"(r) : "v"(a), "v"(b)); return r;
}
static __device__ __forceinline__ unsigned pkmax(unsigned a, unsigned b) {
  unsigned r; asm("v_pk_max_f16 %0, %1, %2" : "=v"(r) : "v"(a), "v"(b)); return r;
}
static __device__ __forceinline__ unsigned pkadd(unsigned a, unsigned b) {
  unsigned r; asm("v_pk_add_f16 %0, %1, %2" : "=v"(r) : "v"(a), "v"(b)); return r;
}
static __device__ __forceinline__ unsigned short f2h_bits(float f) {
  return __builtin_bit_cast(unsigned short, (_Float16)f);
}
static __device__ __forceinline__ float h2f(unsigned short x) {
  return (float)__builtin_bit_cast(_Float16, x);
}

// k_pre: [0,8) W -> B-frag layout; [8,16) zero out
__global__ __launch_bounds__(256) void k_pre(const float* __restrict__ W,
                                             _Float16* __restrict__ wfrag,
                                             float* __restrict__ out) {
  int b = blockIdx.x, t = threadIdx.x;
  if (b < 8) {
    int h = b;
    for (int pos = t; pos < 2048; pos += 256) {
      int kt = pos >> 8, ct = (pos >> 6) & 3, l = pos & 63;
      int lr = l & 15, lg = l >> 4;
#pragma unroll
      for (int e = 0; e < 8; ++e)
        wfrag[(size_t)(((h*8 + kt)*4 + ct)*64 + l) * 8 + e]
          = (_Float16)W[(size_t)(h*256 + kt*32 + lg*8 + e) * 64 + ct*16 + lr];
    }
  } else {
    float4* oz = ((float4*)out) + (size_t)(b - 8) * 8192;
    float4 zz = make_float4(0.f, 0.f, 0.f, 0.f);
    for (int q = t; q < 8192; q += 256) oz[q] = zz;
  }
}

// k_main: ballot and GEMM blocks INTERLEAVED in dispatch order (b%5==4 -> GEMM)
__global__ __launch_bounds__(256) void k_main(
    const float* __restrict__ X, const int* __restrict__ adj,
    const _Float16* __restrict__ wfrag, const float* __restrict__ a,
    unsigned long long* __restrict__ bits, _Float16* __restrict__ bfrag,
    float* __restrict__ f1, _Float16* __restrict__ Gp, _Float16* __restrict__ Gn) {
  int b = blockIdx.x, t = threadIdx.x;
  if ((b % 5) != 4) {
    int b2 = (b / 5) * 4 + (b % 5);                // ballot index 0..2047
    int lane = t & 63;
    int waveid = b2 * 4 + (t >> 6);
#pragma unroll
    for (int it2 = 0; it2 < 8; ++it2) {
      int w0 = waveid + (it2*4 + 0) * 8192;
      int w1 = waveid + (it2*4 + 1) * 8192;
      int w2 = waveid + (it2*4 + 2) * 8192;
      int w3 = waveid + (it2*4 + 3) * 8192;
      int v0 = __builtin_nontemporal_load(adj + (size_t)w0 * 64 + lane);
      int v1 = __builtin_nontemporal_load(adj + (size_t)w1 * 64 + lane);
      int v2 = __builtin_nontemporal_load(adj + (size_t)w2 * 64 + lane);
      int v3 = __builtin_nontemporal_load(adj + (size_t)w3 * 64 + lane);
      unsigned long long m0 = __ballot(v0 != 0);
      unsigned long long m1 = __ballot(v1 != 0);
      unsigned long long m2 = __ballot(v2 != 0);
      unsigned long long m3 = __ballot(v3 != 0);
      if (lane == 0) { bits[w0] = m0; bits[w1] = m1; bits[w2] = m2; bits[w3] = m3; }
    }
    return;
  }
  int b2 = b / 5;                                  // GEMM index 0..511
  int h = b2 & 7, rb = b2 >> 3;
  int w = t >> 6, l = t & 63;
  int i0 = rb * 64 + w * 16;                       // 16 rows per wave
  int r = l & 15, g = l >> 4;
  const U4* wv = (const U4*)wfrag;
  f32x4 z = {0.f, 0.f, 0.f, 0.f};
  f32x4 acc[4] = {z, z, z, z};
#pragma unroll
  for (int kt = 0; kt < 8; ++kt) {
    const float4* xr = (const float4*)(X + (size_t)(i0 + r) * 256 + (kt*4 + g) * 8);
    float4 x0 = xr[0], x1 = xr[1];
    U4 af;
    af.h[0] = (_Float16)x0.x; af.h[1] = (_Float16)x0.y;
    af.h[2] = (_Float16)x0.z; af.h[3] = (_Float16)x0.w;
    af.h[4] = (_Float16)x1.x; af.h[5] = (_Float16)x1.y;
    af.h[6] = (_Float16)x1.z; af.h[7] = (_Float16)x1.w;
#pragma unroll
    for (int ct = 0; ct < 4; ++ct) {
      U4 bv = wv[((h*8 + kt)*4 + ct)*64 + l];
      acc[ct] = __builtin_amdgcn_mfma_f32_16x16x32_f16(af.h, bv.h, acc[ct], 0, 0, 0);
    }
  }
  int jb = i0 + g*4;
#pragma unroll
  for (int ct = 0; ct < 4; ++ct) {
    size_t base = ((((size_t)h*128 + (jb>>5))*4 + ct)*64 + ((jb>>3)&3)*16 + r) * 8
                  + (jb & 7);
    union { short4 s; _Float16 hh[4]; } sv;
#pragma unroll
    for (int ri = 0; ri < 4; ++ri) sv.hh[ri] = (_Float16)acc[ct][ri];
    *(short4*)(bfrag + base) = sv.s;
  }
  float a1v[4], a2v[4];
#pragma unroll
  for (int ct = 0; ct < 4; ++ct) {
    a1v[ct] = a[h*128 + ct*16 + r];
    a2v[ct] = a[h*128 + 64 + ct*16 + r];
  }
#pragma unroll
  for (int ri = 0; ri < 4; ++ri) {
    float s1 = acc[0][ri]*a1v[0] + acc[1][ri]*a1v[1]
             + acc[2][ri]*a1v[2] + acc[3][ri]*a1v[3];
    float s2 = acc[0][ri]*a2v[0] + acc[1][ri]*a2v[1]
             + acc[2][ri]*a2v[2] + acc[3][ri]*a2v[3];
#pragma unroll
    for (int off = 1; off < 16; off <<= 1) {
      s1 += __shfl_xor(s1, off);
      s2 += __shfl_xor(s2, off);
    }
    if (r == 0) {
      int row = i0 + g*4 + ri;
      f1[h*4096 + row] = s1;
      Gp[h*4096 + row] = (_Float16)__expf(s2);
      Gn[h*4096 + row] = (_Float16)__expf(ALPHA * s2);
    }
  }
}

// v6 body, rh removed (wave owns all 32 block rows)
#define ATTN_BODY(PF, JT, DOPF) {                                              \
  U4 gp, gn;                                                                   \
  gp.u = Gs0[(JT)*4 + g].u;                                                    \
  gn.u = Gs1[(JT)*4 + g].u;                                                    \
  U4 b0, b1, b2, b3;                                                           \
  b0.u = PF[0]; b1.u = PF[1]; b2.u = PF[2]; b3.u = PF[3];                      \
  _Pragma("unroll")                                                            \
  for (int rg = 0; rg < 2; ++rg) {                                             \
    unsigned wm = Lb[rg*16 + r][JT];                                           \
    U4 av;                                                                     \
    _Pragma("unroll")                                                          \
    for (int p = 0; p < 4; ++p) {                                              \
      unsigned pm = pkmax(pkmul(Epp[rg], gp.w[p]), pkmul(Enn[rg], gn.w[p]));   \
      av.w[p] = pm & MLUT[(wm >> (g8 + 2*p)) & 3u];                            \
    }                                                                          \
    acc[rg][0] = __builtin_amdgcn_mfma_f32_16x16x32_f16(av.h, b0.h, acc[rg][0], 0,0,0); \
    acc[rg][1] = __builtin_amdgcn_mfma_f32_16x16x32_f16(av.h, b1.h, acc[rg][1], 0,0,0); \
    acc[rg][2] = __builtin_amdgcn_mfma_f32_16x16x32_f16(av.h, b2.h, acc[rg][2], 0,0,0); \
    acc[rg][3] = __builtin_amdgcn_mfma_f32_16x16x32_f16(av.h, b3.h, acc[rg][3], 0,0,0); \
    unsigned sden = pkadd(pkadd(av.w[0], av.w[1]), pkadd(av.w[2], av.w[3]));   \
    den[rg] += h2f((unsigned short)(sden & 0xFFFFu))                           \
             + h2f((unsigned short)(sden >> 16));                              \
  }                                                                            \
  if (DOPF) {                                                                  \
    _Pragma("unroll")                                                          \
    for (int c = 0; c < 4; ++c) PF[c] = bfh[((JT) + 2)*256 + c*64];            \
  }                                                                            \
}

#define WRBUF(i) {                                                             \
  _Pragma("unroll")                                                            \
  for (int rg = 0; rg < 2; ++rg)                                               \
    _Pragma("unroll")                                                          \
    for (int ct = 0; ct < 4; ++ct) redp[(i)*576 + (rg*4+ct)*64 + l] = acc[rg][ct]; \
  f32x4 dv = {den[0], den[1], 0.f, 0.f};                                       \
  redp[(i)*576 + 512 + l] = dv;                                                \
}
#define ADBUF(i) {                                                             \
  _Pragma("unroll")                                                            \
  for (int rg = 0; rg < 2; ++rg)                                               \
    _Pragma("unroll")                                                          \
    for (int ct = 0; ct < 4; ++ct) acc[rg][ct] += redp[(i)*576 + (rg*4+ct)*64 + l]; \
  f32x4 dv = redp[(i)*576 + 512 + l];                                          \
  den[0] += dv[0]; den[1] += dv[1];                                            \
}

// k_attn v14: 32-row blocks x 256 thr (4 waves = 4 jq, each wave owns all
// 32 rows). Same per-wave work/registers/B-traffic as v13, but grid 1024
// (4 blocks/CU), LDS 32.9 KB -> up to 16 waves/CU and finer tail quanta.
__global__ __launch_bounds__(256, 4) void k_attn(
    const float* __restrict__ f1, const unsigned int* __restrict__ adjbits,
    const _Float16* __restrict__ Gp, const _Float16* __restrict__ Gn,
    const _Float16* __restrict__ bfrag, float* __restrict__ out) {
  __shared__ __align__(16) char smem[32896];
  __shared__ unsigned MLUT[4];
  unsigned (*Lb)[129] = (unsigned(*)[129])smem;    // 16512 B adjacency bits
  U4* Gs0 = (U4*)(smem + 16512);                   // 8 KB exp(f2)
  U4* Gs1 = (U4*)(smem + 24704);                   // 8 KB exp(a*f2)
  f32x4* redp = (f32x4*)smem;                      // overlay after main loop
  int b = blockIdx.x;
  int h = b & 7, rs = b >> 3;                      // head <-> XCD; 128 rowblocks
  int i0 = rs * 32;
  int t = threadIdx.x, jq = t >> 6, l = t & 63;
  int r = l & 15, g = l >> 4, g8 = g * 8;
  if (t < 4) MLUT[t] = ((t & 1) ? 0xFFFFu : 0u) | ((t & 2) ? 0xFFFF0000u : 0u);
  // B prefetch issued before staging (latency hidden under LDS fills)
  const uint4* bfh = (const uint4*)bfrag + (size_t)h * 32768 + l;
  int jt0 = jq * 32;
  uint4 pA[4], pB[4];
#pragma unroll
  for (int c = 0; c < 4; ++c) pA[c] = bfh[jt0 * 256 + c*64];
#pragma unroll
  for (int c = 0; c < 4; ++c) pB[c] = bfh[(jt0 + 1) * 256 + c*64];
  for (int q = t; q < 4096; q += 256)
    Lb[q >> 7][q & 127] = adjbits[(size_t)(i0 + (q >> 7)) * 128 + (q & 127)];
  {
    const uint4* gp4 = (const uint4*)(Gp + (size_t)h * 4096);
    const uint4* gn4 = (const uint4*)(Gn + (size_t)h * 4096);
    for (int q = t; q < 512; q += 256) {           // full 512-entry stage
      Gs0[q].u = gp4[q];
      Gs1[q].u = gn4[q];
    }
  }
  unsigned Epp[2], Enn[2];
#pragma unroll
  for (int rg = 0; rg < 2; ++rg) {
    float f1r = f1[h * N_NODES + i0 + rg*16 + r];
    unsigned short ep = f2h_bits(__expf(f1r));
    unsigned short en = f2h_bits(__expf(ALPHA * f1r));
    Epp[rg] = ep | ((unsigned)ep << 16);
    Enn[rg] = en | ((unsigned)en << 16);
  }
  __syncthreads();
  f32x4 z = {0.f,0.f,0.f,0.f};
  f32x4 acc[2][4] = {{z,z,z,z},{z,z,z,z}};
  float den[2] = {0.f, 0.f};
  for (int q2 = 0; q2 < 16; ++q2) {
    ATTN_BODY(pA, jt0 + q2*2,     (q2 < 15));
    ATTN_BODY(pB, jt0 + q2*2 + 1, (q2 < 15));
  }
  __syncthreads();                                 // Lb/Gs dead; redp overlays
  // cross-jq tree: jq1->buf0, jq3->buf1; jq0/jq2 add; jq2->buf0; jq0 adds
  if (jq == 1) WRBUF(0);
  if (jq == 3) WRBUF(1);
  __syncthreads();
  if (jq == 0) ADBUF(0);
  if (jq == 2) ADBUF(1);
  __syncthreads();
  if (jq == 2) WRBUF(0);
  __syncthreads();
  if (jq == 0) {
    ADBUF(0);
#pragma unroll
    for (int rg = 0; rg < 2; ++rg) {
      den[rg] += __shfl_xor(den[rg], 16);
      den[rg] += __shfl_xor(den[rg], 32);          // all lanes: den of row l&15
    }
#pragma unroll
    for (int rg = 0; rg < 2; ++rg)
#pragma unroll
      for (int ri = 0; ri < 4; ++ri) {
        float dr = __shfl(den[rg], g*4 + ri);      // lane g*4+ri holds that row
        float sc = 0.125f / dr;
        float* op = out + (size_t)(i0 + rg*16 + g*4 + ri) * 64;
        atomicAdd(op + r,      acc[rg][0][ri] * sc);
        atomicAdd(op + 16 + r, acc[rg][1][ri] * sc);
        atomicAdd(op + 32 + r, acc[rg][2][ri] * sc);
        atomicAdd(op + 48 + r, acc[rg][3][ri] * sc);
      }
  }
}

extern "C" void kernel_launch(void* const* d_in, const int* in_sizes, int n_in,
                              void* d_out, int out_size, void* d_ws, size_t ws_size,
                              hipStream_t stream) {
  const float* X = (const float*)d_in[0];
  const int* adj = (const int*)d_in[1];
  const float* W = (const float*)d_in[2];
  const float* a = (const float*)d_in[3];
  float* out = (float*)d_out;
  char* ws = (char*)d_ws;

  _Float16* wfrag = (_Float16*)(ws + WFRAG_OFF);
  _Float16* bfrag = (_Float16*)(ws + BFRAG_OFF);
  float* f1 = (float*)(ws + F1_OFF);
  _Float16* Gp = (_Float16*)(ws + GP_OFF);
  _Float16* Gn = (_Float16*)(ws + GN_OFF);
  unsigned long long* bits64 = (unsigned long long*)(ws + ADJ_OFF);
  const unsigned int* bits32 = (const unsigned int*)(ws + ADJ_OFF);

  k_pre<<<dim3(16), dim3(256), 0, stream>>>(W, wfrag, out);
  k_main<<<dim3(2560), dim3(256), 0, stream>>>(X, adj, wfrag, a, bits64, bfrag,
                                               f1, Gp, Gn);
  k_attn<<<dim3(1024), dim3(256), 0, stream>>>(f1, bits32, Gp, Gn, bfrag, out);
}